// Round 17
// baseline (291.153 us; speedup 1.0000x reference)
//
#include <hip/hip_runtime.h>

#define N_NODES 100000
#define N_EDGES 1600000
#define IN_DIM 128
#define HID_DIM 128
#define OUT_DIM 64
#define BKT_SHIFT 7
#define BKT_SIZE 128
#define NBKT ((N_NODES + BKT_SIZE - 1) / BKT_SIZE)  // 782
#define B1 1024                                      // hist/scatter blocks
#define CHK (B1 / 256)                               // scan1 chunks per bucket-column
#define HIST_N (NBKT * B1)                           // 800768
#define HIST_N2 (2 * HIST_N)                         // 1601536
#define SOFF (NBKT * CHK)                            // chunk offset of S partition
#define GEMM_BLKS ((N_NODES + 127) / 128)            // 782

typedef float v2f __attribute__((ext_vector_type(2)));
typedef float v4f __attribute__((ext_vector_type(4)));
typedef short v8s __attribute__((ext_vector_type(8)));

// XCD-affine slot permutation: adjacent hist slots belong to same-XCD blocks.
__device__ __forceinline__ int permb(int b) {
  return ((b & 7) * (B1 >> 3)) | (b >> 3);
}

// ---------- helpers ----------
__device__ __forceinline__ unsigned int f2bf(float f) {  // fp32->bf16 RNE
  unsigned int u = __float_as_uint(f);
  return (u + 0x7FFFu + ((u >> 16) & 1u)) >> 16;
}

template <bool HI>
__device__ __forceinline__ v2f cvt8(unsigned int u) {
  return __builtin_amdgcn_cvt_pk_f32_fp8((int)u, HI);  // word-select immediate
}

__device__ __forceinline__ float wdec(unsigned int p) {  // bf16 weight, bits [17,32)
  return __uint_as_float((p >> 17) << 16);
}

__device__ __forceinline__ void load4(const void* ei, int is64, int half, int base,
                                      int* v) {
  if (is64) {
    const long long* e = (const long long*)ei + (size_t)half * N_EDGES + base;
    longlong2 a = *(const longlong2*)e;
    longlong2 b = *(const longlong2*)(e + 2);
    v[0] = (int)a.x; v[1] = (int)a.y; v[2] = (int)b.x; v[3] = (int)b.y;
  } else {
    const int* e = (const int*)ei + (size_t)half * N_EDGES + base;
    int4 a = *(const int4*)e;
    v[0] = a.x; v[1] = a.y; v[2] = a.z; v[3] = a.w;
  }
}

// block-local int64 detection: odd dwords of first 256 int64 entries all zero
__device__ __forceinline__ int detect64_block(const unsigned int* ei, int* sh) {
  if (threadIdx.x == 0) *sh = 0;
  __syncthreads();
  if (ei[1 + 2 * threadIdx.x] != 0u) *sh = 1;
  __syncthreads();
  return (*sh == 0) ? 1 : 0;
}

// ---------- front kernel: blocks [0,782) = raw GEMM; [782,782+B1) = hist ----------
__global__ __launch_bounds__(256) void front_kernel(const float* __restrict__ x,
                                                    const float* __restrict__ W,
                                                    const void* ei,
                                                    unsigned int* __restrict__ G,
                                                    int* hist, float* S) {
  __shared__ __align__(16) char smem[2 * 128 * 136 * 2];  // 69632 B
  if (blockIdx.x >= GEMM_BLKS) {
    // ---- hist role ----
    int* hd = (int*)smem;           // NBKT
    int* hs = hd + NBKT;            // NBKT
    int* sh = hs + NBKT;
    const int hb = blockIdx.x - GEMM_BLKS;
    const int pj = permb(hb);       // XCD-affine slot
    if (hb == 0 && threadIdx.x < HID_DIM) S[threadIdx.x] = 0.f;
    const int is64 = detect64_block((const unsigned int*)ei, sh);
    for (int k = threadIdx.x; k < NBKT; k += 256) { hd[k] = 0; hs[k] = 0; }
    __syncthreads();
    for (int g = hb * 256 + threadIdx.x; g < N_EDGES / 4; g += B1 * 256) {
      int r[4], c[4];
      load4(ei, is64, 0, g * 4, r);
      load4(ei, is64, 1, g * 4, c);
#pragma unroll
      for (int k = 0; k < 4; k++) {
        atomicAdd(&hd[c[k] >> BKT_SHIFT], 1);
        atomicAdd(&hs[r[k] >> BKT_SHIFT], 1);
      }
    }
    __syncthreads();
    for (int k = threadIdx.x; k < NBKT; k += 256) {
      hist[k * B1 + pj] = hd[k];
      hist[HIST_N + k * B1 + pj] = hs[k];
    }
    return;
  }
  // ---- gemm role: G_raw(fp8) = x @ W1, bf16 MFMA ----
  typedef unsigned short us_row[136];
  us_row* lx = (us_row*)smem;
  us_row* lwt = (us_row*)(smem + 128 * 136 * 2);
  const int t = threadIdx.x;
  const int row0 = blockIdx.x * 128;

  {  // stage W^T bf16
    const float4* W4 = (const float4*)W;
    for (int it = 0; it < 16; ++it) {
      int idx = t + 256 * it;  // k*32 + c4
      int k = idx >> 5, c4 = (idx & 31) * 4;
      float4 w = W4[idx];
      lwt[c4 + 0][k] = (unsigned short)f2bf(w.x);
      lwt[c4 + 1][k] = (unsigned short)f2bf(w.y);
      lwt[c4 + 2][k] = (unsigned short)f2bf(w.z);
      lwt[c4 + 3][k] = (unsigned short)f2bf(w.w);
    }
  }
  {  // stage x tile bf16
    const float4* x4 = (const float4*)(x + (size_t)row0 * IN_DIM);
    for (int it = 0; it < 16; ++it) {
      int idx = t + 256 * it;  // r*32 + kq4
      int r = idx >> 5, kq = (idx & 31) * 4;
      float4 v = make_float4(0.f, 0.f, 0.f, 0.f);
      if (row0 + r < N_NODES) v = x4[idx];
      unsigned int p0 = (f2bf(v.y) << 16) | f2bf(v.x);
      unsigned int p1 = (f2bf(v.w) << 16) | f2bf(v.z);
      *(uint2*)&lx[r][kq] = make_uint2(p0, p1);
    }
  }
  __syncthreads();

  const int lane = t & 63;
  const int wv = t >> 6;
  const int m0 = wv * 32;
  const int lrow = lane & 15;
  const int lk = (lane >> 4) * 8;

  v4f acc[2][8];
#pragma unroll
  for (int si = 0; si < 2; si++)
#pragma unroll
    for (int n = 0; n < 8; n++) acc[si][n] = (v4f){0.f, 0.f, 0.f, 0.f};

#pragma unroll
  for (int kk = 0; kk < 128; kk += 32) {
    v8s a0 = *(const v8s*)&lx[m0 + lrow][kk + lk];
    v8s a1 = *(const v8s*)&lx[m0 + 16 + lrow][kk + lk];
#pragma unroll
    for (int n = 0; n < 8; n++) {
      v8s b = *(const v8s*)&lwt[n * 16 + lrow][kk + lk];
      acc[0][n] = __builtin_amdgcn_mfma_f32_16x16x32_bf16(a0, b, acc[0][n], 0, 0, 0);
      acc[1][n] = __builtin_amdgcn_mfma_f32_16x16x32_bf16(a1, b, acc[1][n], 0, 0, 0);
    }
  }

  unsigned char* G8 = (unsigned char*)G;
#pragma unroll
  for (int si = 0; si < 2; si++)
#pragma unroll
    for (int n = 0; n < 8; n++) {
      int colg = n * 16 + (lane & 15);
#pragma unroll
      for (int i = 0; i < 4; i++) {
        int r = row0 + m0 + si * 16 + (lane >> 4) * 4 + i;
        if (r < N_NODES) {
          float v = acc[si][n][i];
          int pk = __builtin_amdgcn_cvt_pk_fp8_f32(v, v, 0, false);
          G8[(size_t)r * HID_DIM + colg] = (unsigned char)(pk & 0xFF);
        }
      }
    }
}

// ---------- scan1: per-256-chunk exclusive partials + chunk sums ----------
__global__ void scan1_kernel(int* arr, int* bsum, int n) {
  __shared__ int tmp[256];
  int i = blockIdx.x * 256 + threadIdx.x;
  int v = (i < n) ? arr[i] : 0;
  tmp[threadIdx.x] = v;
  __syncthreads();
  for (int off = 1; off < 256; off <<= 1) {
    int t2 = (threadIdx.x >= off) ? tmp[threadIdx.x - off] : 0;
    __syncthreads();
    tmp[threadIdx.x] += t2;
    __syncthreads();
  }
  if (i < n) arr[i] = tmp[threadIdx.x] - v;  // exclusive within chunk
  if (threadIdx.x == 255) bsum[blockIdx.x] = tmp[255];
}

// ---------- scan2: exclusive scan of up to 8192 chunk sums (8/thread) ----------
__global__ void scan2_kernel(int* bsum, int nb) {
  __shared__ int tmp[1024];
  const int t = threadIdx.x;  // 1024
  int v[8];
  int s = 0;
#pragma unroll
  for (int j = 0; j < 8; j++) {
    int idx = 8 * t + j;
    v[j] = (idx < nb) ? bsum[idx] : 0;
    s += v[j];
  }
  tmp[t] = s;
  __syncthreads();
  for (int off = 1; off < 1024; off <<= 1) {
    int t2 = (t >= off) ? tmp[t - off] : 0;
    __syncthreads();
    tmp[t] += t2;
    __syncthreads();
  }
  int excl = tmp[t] - s;
#pragma unroll
  for (int j = 0; j < 8; j++) {
    int idx = 8 * t + j;
    if (idx < nb) bsum[idx] = excl;
    excl += v[j];
  }
}

// ---------- scatter: pairs into bucket partitions; XCD-affine slots ----------
__global__ __launch_bounds__(256) void scatter_kernel(const void* ei, const int* hist,
                                                      const int* bsum,
                                                      unsigned int* pairs) {
  __shared__ int cd[NBKT], cs[NBKT], sh[1];
  const int is64 = detect64_block((const unsigned int*)ei, sh);
  const int pj = permb(blockIdx.x);
  const int pchk = pj >> 8;  // which 256-chunk of the bucket column
  for (int k = threadIdx.x; k < NBKT; k += 256) {
    cd[k] = hist[k * B1 + pj] + bsum[k * CHK + pchk];
    cs[k] = hist[HIST_N + k * B1 + pj] + bsum[SOFF + k * CHK + pchk];
  }
  __syncthreads();
  for (int g = blockIdx.x * 256 + threadIdx.x; g < N_EDGES / 4; g += B1 * 256) {
    int r[4], c[4];
    load4(ei, is64, 0, g * 4, r);
    load4(ei, is64, 1, g * 4, c);
#pragma unroll
    for (int k = 0; k < 4; k++) {
      int pd = atomicAdd(&cd[c[k] >> BKT_SHIFT], 1);
      pairs[pd] = ((unsigned int)(c[k] & (BKT_SIZE - 1)) << 17) | (unsigned int)r[k];
      int ps = atomicAdd(&cs[r[k] >> BKT_SHIFT], 1);
      pairs[ps] = ((unsigned int)(r[k] & (BKT_SIZE - 1)) << 17) | (unsigned int)c[k];
    }
  }
}

// ---------- csrA: per-bucket count + scan -> rowptr + dinv (no scatter) ----------
__global__ __launch_bounds__(256) void csrA_kernel(const int* hist, const int* bsum,
                                                   const unsigned int* pairs,
                                                   int* rowptr, float* dinv) {
  __shared__ int cnt[BKT_SIZE], sc[BKT_SIZE];
  const int k = blockIdx.x;
  const int base = hist[k * B1] + bsum[k * CHK];
  const int end =
      (k == NBKT - 1) ? N_EDGES : hist[(k + 1) * B1] + bsum[(k + 1) * CHK];
  const int nseg = end - base;
  const int l = threadIdx.x;
  if (l < BKT_SIZE) cnt[l] = 0;
  __syncthreads();
  for (int i = l; i < nseg; i += 256) atomicAdd(&cnt[pairs[base + i] >> 17], 1);
  __syncthreads();
  if (l < BKT_SIZE) sc[l] = cnt[l];
  __syncthreads();
  for (int off = 1; off < BKT_SIZE; off <<= 1) {
    int v = (l < BKT_SIZE && l >= off) ? sc[l - off] : 0;
    __syncthreads();
    if (l < BKT_SIZE) sc[l] += v;
    __syncthreads();
  }
  if (l < BKT_SIZE) {
    int excl = sc[l] - cnt[l];
    int v = k * BKT_SIZE + l;
    if (v < N_NODES) {
      rowptr[v] = base + excl;
      dinv[v] = rsqrtf((float)(cnt[l] + 1));
    }
  }
  if (k == NBKT - 1 && l == 0) rowptr[N_NODES] = N_EDGES;
}

// ---------- csrB + outsum fused (role by blockIdx) ----------
__global__ __launch_bounds__(256) void csrBout_kernel(const int* hist, const int* bsum,
                                                      const unsigned int* pairs,
                                                      const int* __restrict__ rowptr,
                                                      const float* __restrict__ dinv,
                                                      unsigned int* __restrict__ csr,
                                                      float* __restrict__ wacc) {
  if (blockIdx.x < NBKT) {
    // ---- csrB role: scatter with bf16(dinv[src]) packed ----
    __shared__ int cur[BKT_SIZE];
    const int k = blockIdx.x;
    const int base = hist[k * B1] + bsum[k * CHK];
    const int end =
        (k == NBKT - 1) ? N_EDGES : hist[(k + 1) * B1] + bsum[(k + 1) * CHK];
    const int nseg = end - base;
    const int l = threadIdx.x;
    if (l < BKT_SIZE) {
      int v = k * BKT_SIZE + l;
      cur[l] = (v < N_NODES) ? rowptr[v] : 0;
    }
    __syncthreads();
    for (int i = l; i < nseg; i += 256) {
      unsigned int pk = pairs[base + i];
      unsigned int src = pk & 0x1FFFFu;
      int pos = atomicAdd(&cur[pk >> 17], 1);
      unsigned int bits = f2bf(dinv[src]);  // 400KB table, L2-hot here
      csr[pos] = (bits << 17) | src;
    }
    return;
  }
  // ---- outsum role ----
  __shared__ float fb[BKT_SIZE];
  const int k = blockIdx.x - NBKT;
  const int base = hist[HIST_N + k * B1] + bsum[SOFF + k * CHK];
  const int end = (k == NBKT - 1)
                      ? 2 * N_EDGES
                      : hist[HIST_N + (k + 1) * B1] + bsum[SOFF + (k + 1) * CHK];
  if (threadIdx.x < BKT_SIZE) fb[threadIdx.x] = 0.f;
  __syncthreads();
  for (int i = base + threadIdx.x; i < end; i += 256) {
    unsigned int pk = pairs[i];
    atomicAdd(&fb[pk >> 17], dinv[pk & 0x1FFFFu]);
  }
  __syncthreads();
  int v = k * BKT_SIZE + threadIdx.x;
  if (threadIdx.x < BKT_SIZE && v < N_NODES) wacc[v] = fb[threadIdx.x];
}

// ---------- aggregate: r13 loop (2 edges/wave, packed weights) ----------
__global__ __launch_bounds__(256) void aggregate_kernel(
    const unsigned int* __restrict__ G, const int* __restrict__ rowptr,
    const unsigned int* __restrict__ csr, const float* __restrict__ dinv,
    const float* __restrict__ wacc, const float* __restrict__ b1,
    float* __restrict__ S) {
  const int lane = threadIdx.x & 63;
  const int sub = lane & 31;   // col group: cols [4*sub, 4*sub+4)
  const int half = lane >> 5;  // edge parity
  const int wid = blockIdx.x * 4 + (threadIdx.x >> 6);
  const int nwaves = gridDim.x * 4;
  const float4 b = ((const float4*)b1)[sub];
  v2f s01 = {0.f, 0.f}, s23 = {0.f, 0.f};

  for (int c = wid; c < N_NODES; c += nwaves) {
    const int start = rowptr[c];
    const int cnum = rowptr[c + 1] - start;
    const float d = dinv[c];  // wave-uniform
    v2f a01 = {0.f, 0.f}, a23 = {0.f, 0.f};
    if (half == 0) {  // self loop: weight = dinv[c]
      unsigned int g = G[c * 32 + sub];
      a01 = cvt8<false>(g) * d;
      a23 = cvt8<true>(g) * d;
    }
    for (int j0 = 0; j0 < cnum; j0 += 64) {
      unsigned int pkl = 0;
      if (j0 + lane < cnum)
        pkl = __builtin_nontemporal_load(&csr[start + j0 + lane]);
      const int m = min(64, cnum - j0);
      int i = 0;
      for (; i + 8 <= m; i += 8) {
        unsigned int p0 = __shfl(pkl, i + half);
        unsigned int p1 = __shfl(pkl, i + 2 + half);
        unsigned int p2 = __shfl(pkl, i + 4 + half);
        unsigned int p3 = __shfl(pkl, i + 6 + half);
        unsigned int g0 = G[(p0 & 0x1FFFFu) * 32 + sub];
        unsigned int g1 = G[(p1 & 0x1FFFFu) * 32 + sub];
        unsigned int g2 = G[(p2 & 0x1FFFFu) * 32 + sub];
        unsigned int g3 = G[(p3 & 0x1FFFFu) * 32 + sub];
        float w0 = wdec(p0), w1 = wdec(p1), w2 = wdec(p2), w3 = wdec(p3);
        a01 += cvt8<false>(g0) * w0; a23 += cvt8<true>(g0) * w0;
        a01 += cvt8<false>(g1) * w1; a23 += cvt8<true>(g1) * w1;
        a01 += cvt8<false>(g2) * w2; a23 += cvt8<true>(g2) * w2;
        a01 += cvt8<false>(g3) * w3; a23 += cvt8<true>(g3) * w3;
      }
      for (; i + 2 <= m; i += 2) {
        unsigned int p = __shfl(pkl, i + half);
        unsigned int g = G[(p & 0x1FFFFu) * 32 + sub];
        float w = wdec(p);
        a01 += cvt8<false>(g) * w;
        a23 += cvt8<true>(g) * w;
      }
      if (i < m) {  // odd leftover: half-0 lanes only
        unsigned int p = __shfl(pkl, i);
        if (half == 0) {
          unsigned int g = G[(p & 0x1FFFFu) * 32 + sub];
          float w = wdec(p);
          a01 += cvt8<false>(g) * w;
          a23 += cvt8<true>(g) * w;
        }
      }
    }
    // merge upper half into lower
    a01.x += __shfl(a01.x, sub + 32);
    a01.y += __shfl(a01.y, sub + 32);
    a23.x += __shfl(a23.x, sub + 32);
    a23.y += __shfl(a23.y, sub + 32);
    if (half == 0) {
      float wc = d * (wacc[c] + d);  // layer-2 weight
      s01.x += wc * fmaxf(fmaf(d, a01.x, b.x), 0.f);
      s01.y += wc * fmaxf(fmaf(d, a01.y, b.y), 0.f);
      s23.x += wc * fmaxf(fmaf(d, a23.x, b.z), 0.f);
      s23.y += wc * fmaxf(fmaf(d, a23.y, b.w), 0.f);
    }
  }

  __shared__ float ls[HID_DIM];
  if (threadIdx.x < HID_DIM) ls[threadIdx.x] = 0.f;
  __syncthreads();
  if (half == 0) {
    atomicAdd(&ls[4 * sub + 0], s01.x);
    atomicAdd(&ls[4 * sub + 1], s01.y);
    atomicAdd(&ls[4 * sub + 2], s23.x);
    atomicAdd(&ls[4 * sub + 3], s23.y);
  }
  __syncthreads();
  if (threadIdx.x < HID_DIM) atomicAdd(&S[threadIdx.x], ls[threadIdx.x]);
}

// ---------- out[j] = (1/N) * S @ W2 + b2 ----------
__global__ void finish_kernel(const float* __restrict__ S, const float* __restrict__ W2,
                              const float* __restrict__ b2, float* __restrict__ out) {
  int j = threadIdx.x;  // 64
  float acc = 0.f;
  for (int k = 0; k < HID_DIM; k++) acc += S[k] * W2[k * OUT_DIM + j];
  out[j] = acc * (1.0f / N_NODES) + b2[j];
}

extern "C" void kernel_launch(void* const* d_in, const int* in_sizes, int n_in,
                              void* d_out, int out_size, void* d_ws, size_t ws_size,
                              hipStream_t stream) {
  const float* x  = (const float*)d_in[0];
  const void*  ei = d_in[1];
  const float* W1 = (const float*)d_in[2];
  const float* b1 = (const float*)d_in[3];
  const float* W2 = (const float*)d_in[4];
  const float* b2 = (const float*)d_in[5];
  float* out = (float*)d_out;

  char* p = (char*)d_ws;
  size_t off = 0;
  auto alloc = [&](size_t bytes) -> void* {
    void* r = p + off;
    off = (off + bytes + 63) & ~(size_t)63;
    return r;
  };
  int*   hist   = (int*)alloc((size_t)HIST_N2 * 4);                // 6.4 MB
  int*   bsum   = (int*)alloc(8192 * 4);
  unsigned int* pairs = (unsigned int*)alloc((size_t)2 * N_EDGES * 4);  // 12.8 MB
  int*   rowptr = (int*)alloc(((size_t)N_NODES + 1) * 4);
  unsigned int* csr = (unsigned int*)alloc((size_t)N_EDGES * 4);   // 6.4 MB
  float* dinv   = (float*)alloc((size_t)N_NODES * 4);
  float* wacc   = (float*)alloc((size_t)N_NODES * 4);
  float* S      = (float*)alloc(HID_DIM * 4);
  unsigned int* G = (unsigned int*)alloc((size_t)N_NODES * HID_DIM);  // 12.8 MB fp8
  (void)ws_size; (void)n_in; (void)in_sizes; (void)out_size;

  const int NBH = HIST_N2 / 256;  // 6256, exact

  front_kernel<<<GEMM_BLKS + B1, 256, 0, stream>>>(x, W1, ei, G, hist, S);
  scan1_kernel<<<NBH, 256, 0, stream>>>(hist, bsum, HIST_N2);
  scan2_kernel<<<1, 1024, 0, stream>>>(bsum, NBH);
  scatter_kernel<<<B1, 256, 0, stream>>>(ei, hist, bsum, pairs);
  csrA_kernel<<<NBKT, 256, 0, stream>>>(hist, bsum, pairs, rowptr, dinv);
  csrBout_kernel<<<2 * NBKT, 256, 0, stream>>>(hist, bsum, pairs, rowptr, dinv, csr,
                                               wacc);
  aggregate_kernel<<<2048, 256, 0, stream>>>(G, rowptr, csr, dinv, wacc, b1, S);
  finish_kernel<<<1, 64, 0, stream>>>(S, W2, b2, out);
}

// Round 18
// 289.972 us; speedup vs baseline: 1.0041x; 1.0041x over previous
//
#include <hip/hip_runtime.h>

#define N_NODES 100000
#define N_EDGES 1600000
#define IN_DIM 128
#define HID_DIM 128
#define OUT_DIM 64
#define BKT_SHIFT 7
#define BKT_SIZE 128
#define NBKT ((N_NODES + BKT_SIZE - 1) / BKT_SIZE)  // 782
#define B1 256                                       // hist/scatter blocks
#define HIST_N (NBKT * B1)                           // 200192
#define HIST_N2 (2 * HIST_N)                         // 400384
#define GEMM_BLKS ((N_NODES + 127) / 128)            // 782

typedef float v2f __attribute__((ext_vector_type(2)));
typedef float v4f __attribute__((ext_vector_type(4)));
typedef short v8s __attribute__((ext_vector_type(8)));

// XCD-affine slot permutation: adjacent hist slots belong to same-XCD blocks.
__device__ __forceinline__ int permb(int b) { return ((b & 7) << 5) | (b >> 3); }

// ---------- helpers ----------
__device__ __forceinline__ unsigned int f2bf(float f) {  // fp32->bf16 RNE
  unsigned int u = __float_as_uint(f);
  return (u + 0x7FFFu + ((u >> 16) & 1u)) >> 16;
}

template <bool HI>
__device__ __forceinline__ v2f cvt8(unsigned int u) {
  return __builtin_amdgcn_cvt_pk_f32_fp8((int)u, HI);  // word-select immediate
}

__device__ __forceinline__ float wdec(unsigned int p) {  // bf16 weight, bits [17,32)
  return __uint_as_float((p >> 17) << 16);
}

__device__ __forceinline__ void load4(const void* ei, int is64, int half, int base,
                                      int* v) {
  if (is64) {
    const long long* e = (const long long*)ei + (size_t)half * N_EDGES + base;
    longlong2 a = *(const longlong2*)e;
    longlong2 b = *(const longlong2*)(e + 2);
    v[0] = (int)a.x; v[1] = (int)a.y; v[2] = (int)b.x; v[3] = (int)b.y;
  } else {
    const int* e = (const int*)ei + (size_t)half * N_EDGES + base;
    int4 a = *(const int4*)e;
    v[0] = a.x; v[1] = a.y; v[2] = a.z; v[3] = a.w;
  }
}

// block-local int64 detection: odd dwords of first 256 int64 entries all zero
__device__ __forceinline__ int detect64_block(const unsigned int* ei, int* sh) {
  if (threadIdx.x == 0) *sh = 0;
  __syncthreads();
  if (ei[1 + 2 * threadIdx.x] != 0u) *sh = 1;
  __syncthreads();
  return (*sh == 0) ? 1 : 0;
}

// ---------- front kernel: blocks [0,782) = raw GEMM; [782,1038) = hist ----------
__global__ __launch_bounds__(256) void front_kernel(const float* __restrict__ x,
                                                    const float* __restrict__ W,
                                                    const void* ei,
                                                    unsigned int* __restrict__ G,
                                                    int* hist, float* S) {
  __shared__ __align__(16) char smem[2 * 128 * 136 * 2];  // 69632 B
  if (blockIdx.x >= GEMM_BLKS) {
    // ---- hist role ----
    int* hd = (int*)smem;           // NBKT
    int* hs = hd + NBKT;            // NBKT
    int* sh = hs + NBKT;
    const int hb = blockIdx.x - GEMM_BLKS;
    const int pj = permb(hb);       // XCD-affine slot
    if (hb == 0 && threadIdx.x < HID_DIM) S[threadIdx.x] = 0.f;
    const int is64 = detect64_block((const unsigned int*)ei, sh);
    for (int k = threadIdx.x; k < NBKT; k += 256) { hd[k] = 0; hs[k] = 0; }
    __syncthreads();
    for (int g = hb * 256 + threadIdx.x; g < N_EDGES / 4; g += B1 * 256) {
      int r[4], c[4];
      load4(ei, is64, 0, g * 4, r);
      load4(ei, is64, 1, g * 4, c);
#pragma unroll
      for (int k = 0; k < 4; k++) {
        atomicAdd(&hd[c[k] >> BKT_SHIFT], 1);
        atomicAdd(&hs[r[k] >> BKT_SHIFT], 1);
      }
    }
    __syncthreads();
    for (int k = threadIdx.x; k < NBKT; k += 256) {
      hist[k * B1 + pj] = hd[k];
      hist[HIST_N + k * B1 + pj] = hs[k];
    }
    return;
  }
  // ---- gemm role: G_raw(fp8) = x @ W1, bf16 MFMA ----
  typedef unsigned short us_row[136];
  us_row* lx = (us_row*)smem;
  us_row* lwt = (us_row*)(smem + 128 * 136 * 2);
  const int t = threadIdx.x;
  const int row0 = blockIdx.x * 128;

  {  // stage W^T bf16
    const float4* W4 = (const float4*)W;
    for (int it = 0; it < 16; ++it) {
      int idx = t + 256 * it;  // k*32 + c4
      int k = idx >> 5, c4 = (idx & 31) * 4;
      float4 w = W4[idx];
      lwt[c4 + 0][k] = (unsigned short)f2bf(w.x);
      lwt[c4 + 1][k] = (unsigned short)f2bf(w.y);
      lwt[c4 + 2][k] = (unsigned short)f2bf(w.z);
      lwt[c4 + 3][k] = (unsigned short)f2bf(w.w);
    }
  }
  {  // stage x tile bf16
    const float4* x4 = (const float4*)(x + (size_t)row0 * IN_DIM);
    for (int it = 0; it < 16; ++it) {
      int idx = t + 256 * it;  // r*32 + kq4
      int r = idx >> 5, kq = (idx & 31) * 4;
      float4 v = make_float4(0.f, 0.f, 0.f, 0.f);
      if (row0 + r < N_NODES) v = x4[idx];
      unsigned int p0 = (f2bf(v.y) << 16) | f2bf(v.x);
      unsigned int p1 = (f2bf(v.w) << 16) | f2bf(v.z);
      *(uint2*)&lx[r][kq] = make_uint2(p0, p1);
    }
  }
  __syncthreads();

  const int lane = t & 63;
  const int wv = t >> 6;
  const int m0 = wv * 32;
  const int lrow = lane & 15;
  const int lk = (lane >> 4) * 8;

  v4f acc[2][8];
#pragma unroll
  for (int si = 0; si < 2; si++)
#pragma unroll
    for (int n = 0; n < 8; n++) acc[si][n] = (v4f){0.f, 0.f, 0.f, 0.f};

#pragma unroll
  for (int kk = 0; kk < 128; kk += 32) {
    v8s a0 = *(const v8s*)&lx[m0 + lrow][kk + lk];
    v8s a1 = *(const v8s*)&lx[m0 + 16 + lrow][kk + lk];
#pragma unroll
    for (int n = 0; n < 8; n++) {
      v8s b = *(const v8s*)&lwt[n * 16 + lrow][kk + lk];
      acc[0][n] = __builtin_amdgcn_mfma_f32_16x16x32_bf16(a0, b, acc[0][n], 0, 0, 0);
      acc[1][n] = __builtin_amdgcn_mfma_f32_16x16x32_bf16(a1, b, acc[1][n], 0, 0, 0);
    }
  }

  unsigned char* G8 = (unsigned char*)G;
#pragma unroll
  for (int si = 0; si < 2; si++)
#pragma unroll
    for (int n = 0; n < 8; n++) {
      int colg = n * 16 + (lane & 15);
#pragma unroll
      for (int i = 0; i < 4; i++) {
        int r = row0 + m0 + si * 16 + (lane >> 4) * 4 + i;
        if (r < N_NODES) {
          float v = acc[si][n][i];
          int pk = __builtin_amdgcn_cvt_pk_fp8_f32(v, v, 0, false);
          G8[(size_t)r * HID_DIM + colg] = (unsigned char)(pk & 0xFF);
        }
      }
    }
}

// ---------- scan1: per-block exclusive partials + block sums ----------
__global__ void scan1_kernel(int* arr, int* bsum, int n) {
  __shared__ int tmp[256];
  int i = blockIdx.x * 256 + threadIdx.x;
  int v = (i < n) ? arr[i] : 0;
  tmp[threadIdx.x] = v;
  __syncthreads();
  for (int off = 1; off < 256; off <<= 1) {
    int t2 = (threadIdx.x >= off) ? tmp[threadIdx.x - off] : 0;
    __syncthreads();
    tmp[threadIdx.x] += t2;
    __syncthreads();
  }
  if (i < n) arr[i] = tmp[threadIdx.x] - v;  // exclusive within block
  if (threadIdx.x == 255) bsum[blockIdx.x] = tmp[255];
}

// ---------- scan2: exclusive scan of up to 2048 block sums (2/thread) ----------
__global__ void scan2_kernel(int* bsum, int nb) {
  __shared__ int tmp[1024];
  const int t = threadIdx.x;  // 1024
  int v0 = (2 * t < nb) ? bsum[2 * t] : 0;
  int v1 = (2 * t + 1 < nb) ? bsum[2 * t + 1] : 0;
  int s = v0 + v1;
  tmp[t] = s;
  __syncthreads();
  for (int off = 1; off < 1024; off <<= 1) {
    int t2 = (t >= off) ? tmp[t - off] : 0;
    __syncthreads();
    tmp[t] += t2;
    __syncthreads();
  }
  int excl = tmp[t] - s;
  if (2 * t < nb) bsum[2 * t] = excl;
  if (2 * t + 1 < nb) bsum[2 * t + 1] = excl + v0;
}

// ---------- scatter: pairs into bucket partitions; XCD-affine slots ----------
__global__ __launch_bounds__(256) void scatter_kernel(const void* ei, const int* hist,
                                                      const int* bsum,
                                                      unsigned int* pairs) {
  __shared__ int cd[NBKT], cs[NBKT], sh[1];
  const int is64 = detect64_block((const unsigned int*)ei, sh);
  const int pj = permb(blockIdx.x);
  for (int k = threadIdx.x; k < NBKT; k += 256) {
    cd[k] = hist[k * B1 + pj] + bsum[k];
    cs[k] = hist[HIST_N + k * B1 + pj] + bsum[NBKT + k];
  }
  __syncthreads();
  for (int g = blockIdx.x * 256 + threadIdx.x; g < N_EDGES / 4; g += B1 * 256) {
    int r[4], c[4];
    load4(ei, is64, 0, g * 4, r);
    load4(ei, is64, 1, g * 4, c);
#pragma unroll
    for (int k = 0; k < 4; k++) {
      int pd = atomicAdd(&cd[c[k] >> BKT_SHIFT], 1);
      pairs[pd] = ((unsigned int)(c[k] & (BKT_SIZE - 1)) << 17) | (unsigned int)r[k];
      int ps = atomicAdd(&cs[r[k] >> BKT_SHIFT], 1);
      pairs[ps] = ((unsigned int)(r[k] & (BKT_SIZE - 1)) << 17) | (unsigned int)c[k];
    }
  }
}

// ---------- csrA: per-bucket count + scan -> rowptr + dinv (no scatter) ----------
__global__ __launch_bounds__(256) void csrA_kernel(const int* hist, const int* bsum,
                                                   const unsigned int* pairs,
                                                   int* rowptr, float* dinv) {
  __shared__ int cnt[BKT_SIZE], sc[BKT_SIZE];
  const int k = blockIdx.x;
  const int base = hist[k * B1] + bsum[k];
  const int end = (k == NBKT - 1) ? N_EDGES : hist[(k + 1) * B1] + bsum[k + 1];
  const int nseg = end - base;
  const int l = threadIdx.x;
  if (l < BKT_SIZE) cnt[l] = 0;
  __syncthreads();
  for (int i = l; i < nseg; i += 256) atomicAdd(&cnt[pairs[base + i] >> 17], 1);
  __syncthreads();
  if (l < BKT_SIZE) sc[l] = cnt[l];
  __syncthreads();
  for (int off = 1; off < BKT_SIZE; off <<= 1) {
    int v = (l < BKT_SIZE && l >= off) ? sc[l - off] : 0;
    __syncthreads();
    if (l < BKT_SIZE) sc[l] += v;
    __syncthreads();
  }
  if (l < BKT_SIZE) {
    int excl = sc[l] - cnt[l];
    int v = k * BKT_SIZE + l;
    if (v < N_NODES) {
      rowptr[v] = base + excl;
      dinv[v] = rsqrtf((float)(cnt[l] + 1));
    }
  }
  if (k == NBKT - 1 && l == 0) rowptr[N_NODES] = N_EDGES;
}

// ---------- csrB + outsum fused (role by blockIdx); NT on last-reader streams ----
__global__ __launch_bounds__(256) void csrBout_kernel(const int* hist, const int* bsum,
                                                      const unsigned int* pairs,
                                                      const int* __restrict__ rowptr,
                                                      const float* __restrict__ dinv,
                                                      unsigned int* __restrict__ csr,
                                                      float* __restrict__ wacc) {
  if (blockIdx.x < NBKT) {
    // ---- csrB role: scatter with bf16(dinv[src]) packed ----
    __shared__ int cur[BKT_SIZE];
    const int k = blockIdx.x;
    const int base = hist[k * B1] + bsum[k];
    const int end = (k == NBKT - 1) ? N_EDGES : hist[(k + 1) * B1] + bsum[k + 1];
    const int nseg = end - base;
    const int l = threadIdx.x;
    if (l < BKT_SIZE) {
      int v = k * BKT_SIZE + l;
      cur[l] = (v < N_NODES) ? rowptr[v] : 0;
    }
    __syncthreads();
    for (int i = l; i < nseg; i += 256) {
      unsigned int pk = __builtin_nontemporal_load(&pairs[base + i]);  // last read
      unsigned int src = pk & 0x1FFFFu;
      int pos = atomicAdd(&cur[pk >> 17], 1);
      unsigned int bits = f2bf(dinv[src]);  // 400KB table, stays L2-hot
      __builtin_nontemporal_store((bits << 17) | src, &csr[pos]);
    }
    return;
  }
  // ---- outsum role ----
  __shared__ float fb[BKT_SIZE];
  const int k = blockIdx.x - NBKT;
  const int base = hist[HIST_N + k * B1] + bsum[NBKT + k];
  const int end =
      (k == NBKT - 1) ? 2 * N_EDGES : hist[HIST_N + (k + 1) * B1] + bsum[NBKT + k + 1];
  if (threadIdx.x < BKT_SIZE) fb[threadIdx.x] = 0.f;
  __syncthreads();
  for (int i = base + threadIdx.x; i < end; i += 256) {
    unsigned int pk = __builtin_nontemporal_load(&pairs[i]);  // only read
    atomicAdd(&fb[pk >> 17], dinv[pk & 0x1FFFFu]);
  }
  __syncthreads();
  int v = k * BKT_SIZE + threadIdx.x;
  if (threadIdx.x < BKT_SIZE && v < N_NODES) wacc[v] = fb[threadIdx.x];
}

// ---------- aggregate: r13 loop (2 edges/wave, packed weights) ----------
__global__ __launch_bounds__(256) void aggregate_kernel(
    const unsigned int* __restrict__ G, const int* __restrict__ rowptr,
    const unsigned int* __restrict__ csr, const float* __restrict__ dinv,
    const float* __restrict__ wacc, const float* __restrict__ b1,
    float* __restrict__ S) {
  const int lane = threadIdx.x & 63;
  const int sub = lane & 31;   // col group: cols [4*sub, 4*sub+4)
  const int half = lane >> 5;  // edge parity
  const int wid = blockIdx.x * 4 + (threadIdx.x >> 6);
  const int nwaves = gridDim.x * 4;
  const float4 b = ((const float4*)b1)[sub];
  v2f s01 = {0.f, 0.f}, s23 = {0.f, 0.f};

  for (int c = wid; c < N_NODES; c += nwaves) {
    const int start = rowptr[c];
    const int cnum = rowptr[c + 1] - start;
    const float d = dinv[c];  // wave-uniform
    v2f a01 = {0.f, 0.f}, a23 = {0.f, 0.f};
    if (half == 0) {  // self loop: weight = dinv[c]
      unsigned int g = G[c * 32 + sub];
      a01 = cvt8<false>(g) * d;
      a23 = cvt8<true>(g) * d;
    }
    for (int j0 = 0; j0 < cnum; j0 += 64) {
      unsigned int pkl = 0;
      if (j0 + lane < cnum)
        pkl = __builtin_nontemporal_load(&csr[start + j0 + lane]);
      const int m = min(64, cnum - j0);
      int i = 0;
      for (; i + 8 <= m; i += 8) {
        unsigned int p0 = __shfl(pkl, i + half);
        unsigned int p1 = __shfl(pkl, i + 2 + half);
        unsigned int p2 = __shfl(pkl, i + 4 + half);
        unsigned int p3 = __shfl(pkl, i + 6 + half);
        unsigned int g0 = G[(p0 & 0x1FFFFu) * 32 + sub];
        unsigned int g1 = G[(p1 & 0x1FFFFu) * 32 + sub];
        unsigned int g2 = G[(p2 & 0x1FFFFu) * 32 + sub];
        unsigned int g3 = G[(p3 & 0x1FFFFu) * 32 + sub];
        float w0 = wdec(p0), w1 = wdec(p1), w2 = wdec(p2), w3 = wdec(p3);
        a01 += cvt8<false>(g0) * w0; a23 += cvt8<true>(g0) * w0;
        a01 += cvt8<false>(g1) * w1; a23 += cvt8<true>(g1) * w1;
        a01 += cvt8<false>(g2) * w2; a23 += cvt8<true>(g2) * w2;
        a01 += cvt8<false>(g3) * w3; a23 += cvt8<true>(g3) * w3;
      }
      for (; i + 2 <= m; i += 2) {
        unsigned int p = __shfl(pkl, i + half);
        unsigned int g = G[(p & 0x1FFFFu) * 32 + sub];
        float w = wdec(p);
        a01 += cvt8<false>(g) * w;
        a23 += cvt8<true>(g) * w;
      }
      if (i < m) {  // odd leftover: half-0 lanes only
        unsigned int p = __shfl(pkl, i);
        if (half == 0) {
          unsigned int g = G[(p & 0x1FFFFu) * 32 + sub];
          float w = wdec(p);
          a01 += cvt8<false>(g) * w;
          a23 += cvt8<true>(g) * w;
        }
      }
    }
    // merge upper half into lower
    a01.x += __shfl(a01.x, sub + 32);
    a01.y += __shfl(a01.y, sub + 32);
    a23.x += __shfl(a23.x, sub + 32);
    a23.y += __shfl(a23.y, sub + 32);
    if (half == 0) {
      float wc = d * (wacc[c] + d);  // layer-2 weight
      s01.x += wc * fmaxf(fmaf(d, a01.x, b.x), 0.f);
      s01.y += wc * fmaxf(fmaf(d, a01.y, b.y), 0.f);
      s23.x += wc * fmaxf(fmaf(d, a23.x, b.z), 0.f);
      s23.y += wc * fmaxf(fmaf(d, a23.y, b.w), 0.f);
    }
  }

  __shared__ float ls[HID_DIM];
  if (threadIdx.x < HID_DIM) ls[threadIdx.x] = 0.f;
  __syncthreads();
  if (half == 0) {
    atomicAdd(&ls[4 * sub + 0], s01.x);
    atomicAdd(&ls[4 * sub + 1], s01.y);
    atomicAdd(&ls[4 * sub + 2], s23.x);
    atomicAdd(&ls[4 * sub + 3], s23.y);
  }
  __syncthreads();
  if (threadIdx.x < HID_DIM) atomicAdd(&S[threadIdx.x], ls[threadIdx.x]);
}

// ---------- out[j] = (1/N) * S @ W2 + b2 ----------
__global__ void finish_kernel(const float* __restrict__ S, const float* __restrict__ W2,
                              const float* __restrict__ b2, float* __restrict__ out) {
  int j = threadIdx.x;  // 64
  float acc = 0.f;
  for (int k = 0; k < HID_DIM; k++) acc += S[k] * W2[k * OUT_DIM + j];
  out[j] = acc * (1.0f / N_NODES) + b2[j];
}

extern "C" void kernel_launch(void* const* d_in, const int* in_sizes, int n_in,
                              void* d_out, int out_size, void* d_ws, size_t ws_size,
                              hipStream_t stream) {
  const float* x  = (const float*)d_in[0];
  const void*  ei = d_in[1];
  const float* W1 = (const float*)d_in[2];
  const float* b1 = (const float*)d_in[3];
  const float* W2 = (const float*)d_in[4];
  const float* b2 = (const float*)d_in[5];
  float* out = (float*)d_out;

  char* p = (char*)d_ws;
  size_t off = 0;
  auto alloc = [&](size_t bytes) -> void* {
    void* r = p + off;
    off = (off + bytes + 63) & ~(size_t)63;
    return r;
  };
  int*   hist   = (int*)alloc((size_t)HIST_N2 * 4);                // 1.6 MB
  int*   bsum   = (int*)alloc(2048 * 4);
  unsigned int* pairs = (unsigned int*)alloc((size_t)2 * N_EDGES * 4);  // 12.8 MB
  int*   rowptr = (int*)alloc(((size_t)N_NODES + 1) * 4);
  unsigned int* csr = (unsigned int*)alloc((size_t)N_EDGES * 4);   // 6.4 MB
  float* dinv   = (float*)alloc((size_t)N_NODES * 4);
  float* wacc   = (float*)alloc((size_t)N_NODES * 4);
  float* S      = (float*)alloc(HID_DIM * 4);
  unsigned int* G = (unsigned int*)alloc((size_t)N_NODES * HID_DIM);  // 12.8 MB fp8
  (void)ws_size; (void)n_in; (void)in_sizes; (void)out_size;

  const int NBH = HIST_N2 / 256;  // 1564, exact

  front_kernel<<<GEMM_BLKS + B1, 256, 0, stream>>>(x, W1, ei, G, hist, S);
  scan1_kernel<<<NBH, 256, 0, stream>>>(hist, bsum, HIST_N2);
  scan2_kernel<<<1, 1024, 0, stream>>>(bsum, NBH);
  scatter_kernel<<<B1, 256, 0, stream>>>(ei, hist, bsum, pairs);
  csrA_kernel<<<NBKT, 256, 0, stream>>>(hist, bsum, pairs, rowptr, dinv);
  csrBout_kernel<<<2 * NBKT, 256, 0, stream>>>(hist, bsum, pairs, rowptr, dinv, csr,
                                               wacc);
  aggregate_kernel<<<2048, 256, 0, stream>>>(G, rowptr, csr, dinv, wacc, b1, S);
  finish_kernel<<<1, 64, 0, stream>>>(S, W2, b2, out);
}

// Round 19
// 271.568 us; speedup vs baseline: 1.0721x; 1.0678x over previous
//
#include <hip/hip_runtime.h>

#define N_NODES 100000
#define N_EDGES 1600000
#define IN_DIM 128
#define HID_DIM 128
#define OUT_DIM 64
#define BKT_SHIFT 7
#define BKT_SIZE 128
#define NBKT ((N_NODES + BKT_SIZE - 1) / BKT_SIZE)  // 782
#define B1 256                                       // hist/scatter blocks
#define HIST_N (NBKT * B1)                           // 200192
#define HIST_N2 (2 * HIST_N)                         // 400384
#define GEMM_BLKS ((N_NODES + 127) / 128)            // 782

typedef float v2f __attribute__((ext_vector_type(2)));
typedef float v4f __attribute__((ext_vector_type(4)));
typedef short v8s __attribute__((ext_vector_type(8)));

// XCD-affine slot permutation: adjacent hist slots belong to same-XCD blocks.
__device__ __forceinline__ int permb(int b) { return ((b & 7) << 5) | (b >> 3); }

// ---------- helpers ----------
__device__ __forceinline__ unsigned int f2bf(float f) {  // fp32->bf16 RNE
  unsigned int u = __float_as_uint(f);
  return (u + 0x7FFFu + ((u >> 16) & 1u)) >> 16;
}

template <bool HI>
__device__ __forceinline__ v2f cvt8(unsigned int u) {
  return __builtin_amdgcn_cvt_pk_f32_fp8((int)u, HI);  // word-select immediate
}

__device__ __forceinline__ float wdec(unsigned int p) {  // bf16 weight, bits [17,32)
  return __uint_as_float((p >> 17) << 16);
}

__device__ __forceinline__ void load4(const void* ei, int is64, int half, int base,
                                      int* v) {
  if (is64) {
    const long long* e = (const long long*)ei + (size_t)half * N_EDGES + base;
    longlong2 a = *(const longlong2*)e;
    longlong2 b = *(const longlong2*)(e + 2);
    v[0] = (int)a.x; v[1] = (int)a.y; v[2] = (int)b.x; v[3] = (int)b.y;
  } else {
    const int* e = (const int*)ei + (size_t)half * N_EDGES + base;
    int4 a = *(const int4*)e;
    v[0] = a.x; v[1] = a.y; v[2] = a.z; v[3] = a.w;
  }
}

// block-local int64 detection: odd dwords of first 256 int64 entries all zero
__device__ __forceinline__ int detect64_block(const unsigned int* ei, int* sh) {
  if (threadIdx.x == 0) *sh = 0;
  __syncthreads();
  if (ei[1 + 2 * threadIdx.x] != 0u) *sh = 1;
  __syncthreads();
  return (*sh == 0) ? 1 : 0;
}

// ---------- front kernel: blocks [0,782) = raw GEMM; [782,1038) = hist ----------
__global__ __launch_bounds__(256) void front_kernel(const float* __restrict__ x,
                                                    const float* __restrict__ W,
                                                    const void* ei,
                                                    unsigned int* __restrict__ G,
                                                    int* hist, float* S) {
  __shared__ __align__(16) char smem[2 * 128 * 136 * 2];  // 69632 B
  if (blockIdx.x >= GEMM_BLKS) {
    // ---- hist role ----
    int* hd = (int*)smem;           // NBKT
    int* hs = hd + NBKT;            // NBKT
    int* sh = hs + NBKT;
    const int hb = blockIdx.x - GEMM_BLKS;
    const int pj = permb(hb);       // XCD-affine slot
    if (hb == 0 && threadIdx.x < HID_DIM) S[threadIdx.x] = 0.f;
    const int is64 = detect64_block((const unsigned int*)ei, sh);
    for (int k = threadIdx.x; k < NBKT; k += 256) { hd[k] = 0; hs[k] = 0; }
    __syncthreads();
    for (int g = hb * 256 + threadIdx.x; g < N_EDGES / 4; g += B1 * 256) {
      int r[4], c[4];
      load4(ei, is64, 0, g * 4, r);
      load4(ei, is64, 1, g * 4, c);
#pragma unroll
      for (int k = 0; k < 4; k++) {
        atomicAdd(&hd[c[k] >> BKT_SHIFT], 1);
        atomicAdd(&hs[r[k] >> BKT_SHIFT], 1);
      }
    }
    __syncthreads();
    for (int k = threadIdx.x; k < NBKT; k += 256) {
      hist[k * B1 + pj] = hd[k];
      hist[HIST_N + k * B1 + pj] = hs[k];
    }
    return;
  }
  // ---- gemm role: G_raw(fp8) = x @ W1, bf16 MFMA ----
  typedef unsigned short us_row[136];
  us_row* lx = (us_row*)smem;
  us_row* lwt = (us_row*)(smem + 128 * 136 * 2);
  const int t = threadIdx.x;
  const int row0 = blockIdx.x * 128;

  {  // stage W^T bf16
    const float4* W4 = (const float4*)W;
    for (int it = 0; it < 16; ++it) {
      int idx = t + 256 * it;  // k*32 + c4
      int k = idx >> 5, c4 = (idx & 31) * 4;
      float4 w = W4[idx];
      lwt[c4 + 0][k] = (unsigned short)f2bf(w.x);
      lwt[c4 + 1][k] = (unsigned short)f2bf(w.y);
      lwt[c4 + 2][k] = (unsigned short)f2bf(w.z);
      lwt[c4 + 3][k] = (unsigned short)f2bf(w.w);
    }
  }
  {  // stage x tile bf16
    const float4* x4 = (const float4*)(x + (size_t)row0 * IN_DIM);
    for (int it = 0; it < 16; ++it) {
      int idx = t + 256 * it;  // r*32 + kq4
      int r = idx >> 5, kq = (idx & 31) * 4;
      float4 v = make_float4(0.f, 0.f, 0.f, 0.f);
      if (row0 + r < N_NODES) v = x4[idx];
      unsigned int p0 = (f2bf(v.y) << 16) | f2bf(v.x);
      unsigned int p1 = (f2bf(v.w) << 16) | f2bf(v.z);
      *(uint2*)&lx[r][kq] = make_uint2(p0, p1);
    }
  }
  __syncthreads();

  const int lane = t & 63;
  const int wv = t >> 6;
  const int m0 = wv * 32;
  const int lrow = lane & 15;
  const int lk = (lane >> 4) * 8;

  v4f acc[2][8];
#pragma unroll
  for (int si = 0; si < 2; si++)
#pragma unroll
    for (int n = 0; n < 8; n++) acc[si][n] = (v4f){0.f, 0.f, 0.f, 0.f};

#pragma unroll
  for (int kk = 0; kk < 128; kk += 32) {
    v8s a0 = *(const v8s*)&lx[m0 + lrow][kk + lk];
    v8s a1 = *(const v8s*)&lx[m0 + 16 + lrow][kk + lk];
#pragma unroll
    for (int n = 0; n < 8; n++) {
      v8s b = *(const v8s*)&lwt[n * 16 + lrow][kk + lk];
      acc[0][n] = __builtin_amdgcn_mfma_f32_16x16x32_bf16(a0, b, acc[0][n], 0, 0, 0);
      acc[1][n] = __builtin_amdgcn_mfma_f32_16x16x32_bf16(a1, b, acc[1][n], 0, 0, 0);
    }
  }

  unsigned char* G8 = (unsigned char*)G;
#pragma unroll
  for (int si = 0; si < 2; si++)
#pragma unroll
    for (int n = 0; n < 8; n++) {
      int colg = n * 16 + (lane & 15);
#pragma unroll
      for (int i = 0; i < 4; i++) {
        int r = row0 + m0 + si * 16 + (lane >> 4) * 4 + i;
        if (r < N_NODES) {
          float v = acc[si][n][i];
          int pk = __builtin_amdgcn_cvt_pk_fp8_f32(v, v, 0, false);
          G8[(size_t)r * HID_DIM + colg] = (unsigned char)(pk & 0xFF);
        }
      }
    }
}

// ---------- scan1: per-block exclusive partials + block sums ----------
__global__ void scan1_kernel(int* arr, int* bsum, int n) {
  __shared__ int tmp[256];
  int i = blockIdx.x * 256 + threadIdx.x;
  int v = (i < n) ? arr[i] : 0;
  tmp[threadIdx.x] = v;
  __syncthreads();
  for (int off = 1; off < 256; off <<= 1) {
    int t2 = (threadIdx.x >= off) ? tmp[threadIdx.x - off] : 0;
    __syncthreads();
    tmp[threadIdx.x] += t2;
    __syncthreads();
  }
  if (i < n) arr[i] = tmp[threadIdx.x] - v;  // exclusive within block
  if (threadIdx.x == 255) bsum[blockIdx.x] = tmp[255];
}

// ---------- scan2: exclusive scan of up to 2048 block sums (2/thread) ----------
__global__ void scan2_kernel(int* bsum, int nb) {
  __shared__ int tmp[1024];
  const int t = threadIdx.x;  // 1024
  int v0 = (2 * t < nb) ? bsum[2 * t] : 0;
  int v1 = (2 * t + 1 < nb) ? bsum[2 * t + 1] : 0;
  int s = v0 + v1;
  tmp[t] = s;
  __syncthreads();
  for (int off = 1; off < 1024; off <<= 1) {
    int t2 = (t >= off) ? tmp[t - off] : 0;
    __syncthreads();
    tmp[t] += t2;
    __syncthreads();
  }
  int excl = tmp[t] - s;
  if (2 * t < nb) bsum[2 * t] = excl;
  if (2 * t + 1 < nb) bsum[2 * t + 1] = excl + v0;
}

// ---------- scatter: pairs into bucket partitions; XCD-affine slots ----------
__global__ __launch_bounds__(256) void scatter_kernel(const void* ei, const int* hist,
                                                      const int* bsum,
                                                      unsigned int* pairs) {
  __shared__ int cd[NBKT], cs[NBKT], sh[1];
  const int is64 = detect64_block((const unsigned int*)ei, sh);
  const int pj = permb(blockIdx.x);
  for (int k = threadIdx.x; k < NBKT; k += 256) {
    cd[k] = hist[k * B1 + pj] + bsum[k];
    cs[k] = hist[HIST_N + k * B1 + pj] + bsum[NBKT + k];
  }
  __syncthreads();
  for (int g = blockIdx.x * 256 + threadIdx.x; g < N_EDGES / 4; g += B1 * 256) {
    int r[4], c[4];
    load4(ei, is64, 0, g * 4, r);
    load4(ei, is64, 1, g * 4, c);
#pragma unroll
    for (int k = 0; k < 4; k++) {
      int pd = atomicAdd(&cd[c[k] >> BKT_SHIFT], 1);
      pairs[pd] = ((unsigned int)(c[k] & (BKT_SIZE - 1)) << 17) | (unsigned int)r[k];
      int ps = atomicAdd(&cs[r[k] >> BKT_SHIFT], 1);
      pairs[ps] = ((unsigned int)(r[k] & (BKT_SIZE - 1)) << 17) | (unsigned int)c[k];
    }
  }
}

// ---------- csrA: per-bucket count + scan -> rowptr + dinv (no scatter) ----------
__global__ __launch_bounds__(256) void csrA_kernel(const int* hist, const int* bsum,
                                                   const unsigned int* pairs,
                                                   int* rowptr, float* dinv) {
  __shared__ int cnt[BKT_SIZE], sc[BKT_SIZE];
  const int k = blockIdx.x;
  const int base = hist[k * B1] + bsum[k];
  const int end = (k == NBKT - 1) ? N_EDGES : hist[(k + 1) * B1] + bsum[k + 1];
  const int nseg = end - base;
  const int l = threadIdx.x;
  if (l < BKT_SIZE) cnt[l] = 0;
  __syncthreads();
  for (int i = l; i < nseg; i += 256) atomicAdd(&cnt[pairs[base + i] >> 17], 1);
  __syncthreads();
  if (l < BKT_SIZE) sc[l] = cnt[l];
  __syncthreads();
  for (int off = 1; off < BKT_SIZE; off <<= 1) {
    int v = (l < BKT_SIZE && l >= off) ? sc[l - off] : 0;
    __syncthreads();
    if (l < BKT_SIZE) sc[l] += v;
    __syncthreads();
  }
  if (l < BKT_SIZE) {
    int excl = sc[l] - cnt[l];
    int v = k * BKT_SIZE + l;
    if (v < N_NODES) {
      rowptr[v] = base + excl;
      dinv[v] = rsqrtf((float)(cnt[l] + 1));
    }
  }
  if (k == NBKT - 1 && l == 0) rowptr[N_NODES] = N_EDGES;
}

// ---------- csrB + outsum fused (role by blockIdx) ----------
__global__ __launch_bounds__(256) void csrBout_kernel(const int* hist, const int* bsum,
                                                      const unsigned int* pairs,
                                                      const int* __restrict__ rowptr,
                                                      const float* __restrict__ dinv,
                                                      unsigned int* __restrict__ csr,
                                                      float* __restrict__ wacc) {
  if (blockIdx.x < NBKT) {
    // ---- csrB role: scatter with bf16(dinv[src]) packed ----
    __shared__ int cur[BKT_SIZE];
    const int k = blockIdx.x;
    const int base = hist[k * B1] + bsum[k];
    const int end = (k == NBKT - 1) ? N_EDGES : hist[(k + 1) * B1] + bsum[k + 1];
    const int nseg = end - base;
    const int l = threadIdx.x;
    if (l < BKT_SIZE) {
      int v = k * BKT_SIZE + l;
      cur[l] = (v < N_NODES) ? rowptr[v] : 0;
    }
    __syncthreads();
    for (int i = l; i < nseg; i += 256) {
      unsigned int pk = pairs[base + i];
      unsigned int src = pk & 0x1FFFFu;
      int pos = atomicAdd(&cur[pk >> 17], 1);
      unsigned int bits = f2bf(dinv[src]);  // 400KB table, L2-hot here
      csr[pos] = (bits << 17) | src;
    }
    return;
  }
  // ---- outsum role ----
  __shared__ float fb[BKT_SIZE];
  const int k = blockIdx.x - NBKT;
  const int base = hist[HIST_N + k * B1] + bsum[NBKT + k];
  const int end =
      (k == NBKT - 1) ? 2 * N_EDGES : hist[HIST_N + (k + 1) * B1] + bsum[NBKT + k + 1];
  if (threadIdx.x < BKT_SIZE) fb[threadIdx.x] = 0.f;
  __syncthreads();
  for (int i = base + threadIdx.x; i < end; i += 256) {
    unsigned int pk = pairs[i];
    atomicAdd(&fb[pk >> 17], dinv[pk & 0x1FFFFu]);
  }
  __syncthreads();
  int v = k * BKT_SIZE + threadIdx.x;
  if (threadIdx.x < BKT_SIZE && v < N_NODES) wacc[v] = fb[threadIdx.x];
}

// ---------- aggregate: r13 loop (2 edges/wave, packed weights) ----------
__global__ __launch_bounds__(256) void aggregate_kernel(
    const unsigned int* __restrict__ G, const int* __restrict__ rowptr,
    const unsigned int* __restrict__ csr, const float* __restrict__ dinv,
    const float* __restrict__ wacc, const float* __restrict__ b1,
    float* __restrict__ S) {
  const int lane = threadIdx.x & 63;
  const int sub = lane & 31;   // col group: cols [4*sub, 4*sub+4)
  const int half = lane >> 5;  // edge parity
  const int wid = blockIdx.x * 4 + (threadIdx.x >> 6);
  const int nwaves = gridDim.x * 4;
  const float4 b = ((const float4*)b1)[sub];
  v2f s01 = {0.f, 0.f}, s23 = {0.f, 0.f};

  for (int c = wid; c < N_NODES; c += nwaves) {
    const int start = rowptr[c];
    const int cnum = rowptr[c + 1] - start;
    const float d = dinv[c];  // wave-uniform
    v2f a01 = {0.f, 0.f}, a23 = {0.f, 0.f};
    if (half == 0) {  // self loop: weight = dinv[c]
      unsigned int g = G[c * 32 + sub];
      a01 = cvt8<false>(g) * d;
      a23 = cvt8<true>(g) * d;
    }
    for (int j0 = 0; j0 < cnum; j0 += 64) {
      unsigned int pkl = 0;
      if (j0 + lane < cnum)
        pkl = __builtin_nontemporal_load(&csr[start + j0 + lane]);
      const int m = min(64, cnum - j0);
      int i = 0;
      for (; i + 8 <= m; i += 8) {
        unsigned int p0 = __shfl(pkl, i + half);
        unsigned int p1 = __shfl(pkl, i + 2 + half);
        unsigned int p2 = __shfl(pkl, i + 4 + half);
        unsigned int p3 = __shfl(pkl, i + 6 + half);
        unsigned int g0 = G[(p0 & 0x1FFFFu) * 32 + sub];
        unsigned int g1 = G[(p1 & 0x1FFFFu) * 32 + sub];
        unsigned int g2 = G[(p2 & 0x1FFFFu) * 32 + sub];
        unsigned int g3 = G[(p3 & 0x1FFFFu) * 32 + sub];
        float w0 = wdec(p0), w1 = wdec(p1), w2 = wdec(p2), w3 = wdec(p3);
        a01 += cvt8<false>(g0) * w0; a23 += cvt8<true>(g0) * w0;
        a01 += cvt8<false>(g1) * w1; a23 += cvt8<true>(g1) * w1;
        a01 += cvt8<false>(g2) * w2; a23 += cvt8<true>(g2) * w2;
        a01 += cvt8<false>(g3) * w3; a23 += cvt8<true>(g3) * w3;
      }
      for (; i + 2 <= m; i += 2) {
        unsigned int p = __shfl(pkl, i + half);
        unsigned int g = G[(p & 0x1FFFFu) * 32 + sub];
        float w = wdec(p);
        a01 += cvt8<false>(g) * w;
        a23 += cvt8<true>(g) * w;
      }
      if (i < m) {  // odd leftover: half-0 lanes only
        unsigned int p = __shfl(pkl, i);
        if (half == 0) {
          unsigned int g = G[(p & 0x1FFFFu) * 32 + sub];
          float w = wdec(p);
          a01 += cvt8<false>(g) * w;
          a23 += cvt8<true>(g) * w;
        }
      }
    }
    // merge upper half into lower
    a01.x += __shfl(a01.x, sub + 32);
    a01.y += __shfl(a01.y, sub + 32);
    a23.x += __shfl(a23.x, sub + 32);
    a23.y += __shfl(a23.y, sub + 32);
    if (half == 0) {
      float wc = d * (wacc[c] + d);  // layer-2 weight
      s01.x += wc * fmaxf(fmaf(d, a01.x, b.x), 0.f);
      s01.y += wc * fmaxf(fmaf(d, a01.y, b.y), 0.f);
      s23.x += wc * fmaxf(fmaf(d, a23.x, b.z), 0.f);
      s23.y += wc * fmaxf(fmaf(d, a23.y, b.w), 0.f);
    }
  }

  __shared__ float ls[HID_DIM];
  if (threadIdx.x < HID_DIM) ls[threadIdx.x] = 0.f;
  __syncthreads();
  if (half == 0) {
    atomicAdd(&ls[4 * sub + 0], s01.x);
    atomicAdd(&ls[4 * sub + 1], s01.y);
    atomicAdd(&ls[4 * sub + 2], s23.x);
    atomicAdd(&ls[4 * sub + 3], s23.y);
  }
  __syncthreads();
  if (threadIdx.x < HID_DIM) atomicAdd(&S[threadIdx.x], ls[threadIdx.x]);
}

// ---------- out[j] = (1/N) * S @ W2 + b2 ----------
__global__ void finish_kernel(const float* __restrict__ S, const float* __restrict__ W2,
                              const float* __restrict__ b2, float* __restrict__ out) {
  int j = threadIdx.x;  // 64
  float acc = 0.f;
  for (int k = 0; k < HID_DIM; k++) acc += S[k] * W2[k * OUT_DIM + j];
  out[j] = acc * (1.0f / N_NODES) + b2[j];
}

extern "C" void kernel_launch(void* const* d_in, const int* in_sizes, int n_in,
                              void* d_out, int out_size, void* d_ws, size_t ws_size,
                              hipStream_t stream) {
  const float* x  = (const float*)d_in[0];
  const void*  ei = d_in[1];
  const float* W1 = (const float*)d_in[2];
  const float* b1 = (const float*)d_in[3];
  const float* W2 = (const float*)d_in[4];
  const float* b2 = (const float*)d_in[5];
  float* out = (float*)d_out;

  char* p = (char*)d_ws;
  size_t off = 0;
  auto alloc = [&](size_t bytes) -> void* {
    void* r = p + off;
    off = (off + bytes + 63) & ~(size_t)63;
    return r;
  };
  int*   hist   = (int*)alloc((size_t)HIST_N2 * 4);                // 1.6 MB
  int*   bsum   = (int*)alloc(2048 * 4);
  unsigned int* pairs = (unsigned int*)alloc((size_t)2 * N_EDGES * 4);  // 12.8 MB
  int*   rowptr = (int*)alloc(((size_t)N_NODES + 1) * 4);
  unsigned int* csr = (unsigned int*)alloc((size_t)N_EDGES * 4);   // 6.4 MB
  float* dinv   = (float*)alloc((size_t)N_NODES * 4);
  float* wacc   = (float*)alloc((size_t)N_NODES * 4);
  float* S      = (float*)alloc(HID_DIM * 4);
  unsigned int* G = (unsigned int*)alloc((size_t)N_NODES * HID_DIM);  // 12.8 MB fp8
  (void)ws_size; (void)n_in; (void)in_sizes; (void)out_size;

  const int NBH = HIST_N2 / 256;  // 1564, exact

  front_kernel<<<GEMM_BLKS + B1, 256, 0, stream>>>(x, W1, ei, G, hist, S);
  scan1_kernel<<<NBH, 256, 0, stream>>>(hist, bsum, HIST_N2);
  scan2_kernel<<<1, 1024, 0, stream>>>(bsum, NBH);
  scatter_kernel<<<B1, 256, 0, stream>>>(ei, hist, bsum, pairs);
  csrA_kernel<<<NBKT, 256, 0, stream>>>(hist, bsum, pairs, rowptr, dinv);
  csrBout_kernel<<<2 * NBKT, 256, 0, stream>>>(hist, bsum, pairs, rowptr, dinv, csr,
                                               wacc);
  aggregate_kernel<<<2048, 256, 0, stream>>>(G, rowptr, csr, dinv, wacc, b1, S);
  finish_kernel<<<1, 64, 0, stream>>>(S, W2, b2, out);
}